// Round 1
// baseline (170.518 us; speedup 1.0000x reference)
//
#include <hip/hip_runtime.h>
#include <hip/hip_cooperative_groups.h>

namespace cg = cooperative_groups;

#define NB 16
#define HH 256
#define WW 256
#define HWSZ (HH * WW)
#define NPIX (NB * HWSZ)
#define ROWS (NB * HH)  // 4096

// ---- fused-kernel ws layout (4-byte units) ----
//   [0, NPIX)                  packed u16 pair per pixel: lo=dN, hi=dP
//   [NPIX + v*NBLK + blk]      P[v][blk], v=0..5: {ce, hard, hard*t, t, poscnt, bnd}
//   [NPIX + 6*NBLK]            ticket counter (u32)
#define NBLK 1024
#define RPB 4  // rows per block
#define OFF_P NPIX
#define OFF_TICKET (NPIX + 6 * NBLK)

// ---- legacy 3-kernel ws layout (fallback path) ----
#define OFF_PL NPIX
#define OFF_PART2 (NPIX + 5 * ROWS)

#define LOG2E 1.44269504088896340736f
#define LN2 0.69314718055994530942f

// softplus(z) = log(1+e^z) = max(z,0) + ln2*log2(1+exp2(-|z|*log2e))
__device__ __forceinline__ float softplus_fast(float z) {
  const float u = __builtin_amdgcn_exp2f(-fabsf(z) * LOG2E);
  return fmaxf(z, 0.0f) + LN2 * __builtin_amdgcn_logf(1.0f + u);
}

// =====================================================================
// Fused single cooperative kernel: 1024 blocks x 256 thr, 4 rows/block.
// Phase1 (row EDT + CE/dice partials) -> grid.sync -> Phase2 (column EDT
// + boundary) -> block reduce -> last-block finalize.
// __launch_bounds__(256,4): <=128 VGPR -> 4 blocks/CU -> exactly 1024
// co-resident blocks on 256 CUs (cooperative-launch requirement).
// =====================================================================
__global__ __launch_bounds__(256, 4) void fused_kernel(
    const float* __restrict__ inp, const int* __restrict__ tgt,
    unsigned int* __restrict__ wsu, float* __restrict__ wsf,
    float* __restrict__ out) {
  const int blk = blockIdx.x;
  const int r0 = blk * RPB;   // first row (b*HH + i)
  const int b = r0 >> 8;      // all 4 rows in same sample (256 % 4 == 0)
  const int i0 = r0 & 255;
  const int j = threadIdx.x;
  const int lane = j & 63, wid = j >> 6;

  if (blk == 0 && j == 0) wsu[OFF_TICKET] = 0u;  // visible after grid.sync

  // ---------------- Phase 1: preload 4 rows, CE/dice, row EDT ----------------
  float x0[RPB], x1[RPB];
  int tt[RPB];
  const size_t base0 = (size_t)(2 * b) * HWSZ + (size_t)i0 * WW + j;
#pragma unroll
  for (int rr = 0; rr < RPB; ++rr) {
    x0[rr] = inp[base0 + (size_t)rr * WW];
    x1[rr] = inp[base0 + (size_t)rr * WW + HWSZ];
    tt[rr] = tgt[(size_t)(r0 + rr) * WW + j];
  }

  float ceAcc = 0.0f;
  int p1 = 0, p2 = 0;  // packed 16-bit: h|ht<<16 ; t|pf<<16 (block sums <= 1024)
  bool posv[RPB], tb[RPB];
#pragma unroll
  for (int rr = 0; rr < RPB; ++rr) {
    const float d = x1[rr] - x0[rr];
    const bool pos = x1[rr] > x0[rr];    // argmax==1 (ties -> class 0)
    const bool hard = x1[rr] >= x0[rr];  // probs1 >= 0.5
    const bool tf = (tt[rr] == 1);
    ceAcc += softplus_fast(tf ? -d : d);
    p1 += (hard ? 1 : 0) | ((hard && tf) ? 0x10000 : 0);
    p2 += (tf ? 1 : 0) | (pos ? 0x10000 : 0);
    posv[rr] = pos;
    tb[rr] = tf;
  }

  // All 4 rows' pos-masks as 4x64-bit ballots, single barrier
  __shared__ unsigned long long wsh[RPB][4];
#pragma unroll
  for (int rr = 0; rr < RPB; ++rr) {
    const unsigned long long bal = __ballot(posv[rr]);
    if (lane == 0) wsh[rr][wid] = bal;
  }
  __syncthreads();

  const int qj = j >> 6, rj = j & 63;
  const unsigned long long lowmask = (~0ull) >> (63 - rj);
  const unsigned long long himask = (~0ull) << rj;

  float mN[RPB], mP[RPB];
#pragma unroll
  for (int rr = 0; rr < RPB; ++rr) {
    unsigned long long wp[4], wn[4];
#pragma unroll
    for (int q = 0; q < 4; ++q) { wp[q] = wsh[rr][q]; wn[q] = ~wp[q]; }

    int loP = -(1 << 20), loN = -(1 << 20);
#pragma unroll
    for (int q = 0; q < 4; ++q) {
      unsigned long long mp = wp[q], mn = wn[q];
      if (q == qj) { mp &= lowmask; mn &= lowmask; }
      else if (q > qj) { mp = 0ull; mn = 0ull; }
      if (mp) loP = (q << 6) + 63 - __builtin_clzll(mp);
      if (mn) loN = (q << 6) + 63 - __builtin_clzll(mn);
    }
    int hiP = (1 << 20), hiN = (1 << 20);
#pragma unroll
    for (int q = 3; q >= 0; --q) {
      unsigned long long mp = wp[q], mn = wn[q];
      if (q == qj) { mp &= himask; mn &= himask; }
      else if (q < qj) { mp = 0ull; mn = 0ull; }
      if (mp) hiP = (q << 6) + (int)__builtin_ctzll(mp);
      if (mn) hiN = (q << 6) + (int)__builtin_ctzll(mn);
    }
    const int dN = min(j - loP, hiP - j);  // dist to nearest pos in row
    const int dP = min(j - loN, hiN - j);  // dist to nearest neg in row
    const unsigned int dNc = (dN > 255) ? 0xFFFFu : (unsigned int)dN;
    const unsigned int dPc = (dP > 255) ? 0xFFFFu : (unsigned int)dP;
    wsu[(size_t)(r0 + rr) * WW + j] = dNc | (dPc << 16);
    const float aN = (float)dNc, aP = (float)dPc;
    mN[rr] = aN * aN;  // r=0 candidates kept in registers (no re-read in phase2)
    mP[rr] = aP * aP;
  }

  // ---------------- grid-wide barrier (replaces kernel boundary) ----------------
  cg::this_grid().sync();

  // ---------------- Phase 2: exact column EDT, 4 rows interleaved ----------------
  // 8 independent loads in flight per iteration; min is monotone so extra
  // (already-converged) row updates are harmless.
  const unsigned int* g = wsu + (size_t)b * HWSZ;
  const int rmax = max(i0 + RPB - 1, 255 - i0);
  for (int r = 1; r <= rmax; ++r) {
    const float rr2 = (float)(r * r);
    bool any = false;
#pragma unroll
    for (int rr = 0; rr < RPB; ++rr)
      any = any || (rr2 < mN[rr]) || (rr2 < mP[rr]);
    if (!__ballot(any)) break;  // whole wave converged on all 4 rows
#pragma unroll
    for (int rr = 0; rr < RPB; ++rr) {
      const int i = i0 + rr;
      if (i - r >= 0) {
        const unsigned int u = g[(size_t)(i - r) * WW + j];
        const float a = (float)(u & 0xFFFFu), bb = (float)(u >> 16);
        mN[rr] = fminf(mN[rr], a * a + rr2);
        mP[rr] = fminf(mP[rr], bb * bb + rr2);
      }
      if (i + r < HH) {
        const unsigned int u = g[(size_t)(i + r) * WW + j];
        const float a = (float)(u & 0xFFFFu), bb = (float)(u >> 16);
        mN[rr] = fminf(mN[rr], a * a + rr2);
        mP[rr] = fminf(mP[rr], bb * bb + rr2);
      }
    }
  }

  float bnd = 0.0f;
#pragma unroll
  for (int rr = 0; rr < RPB; ++rr) {
    // res = dn*neg - (dp-1)*pos
    const float res = posv[rr] ? (1.0f - sqrtf(mP[rr])) : sqrtf(mN[rr]);
    if (tb[rr]) bnd += res;
  }

  // ---------------- single block reduction over all 4 rows ----------------
#pragma unroll
  for (int off = 32; off > 0; off >>= 1) {
    ceAcc += __shfl_down(ceAcc, off);
    bnd += __shfl_down(bnd, off);
    p1 += __shfl_down(p1, off);
    p2 += __shfl_down(p2, off);
  }
  __shared__ float rf[4][2];
  __shared__ int ri[4][2];
  if (lane == 0) { rf[wid][0] = ceAcc; rf[wid][1] = bnd; ri[wid][0] = p1; ri[wid][1] = p2; }
  __syncthreads();
  if (j == 0) {
    float sce = 0.f, sbn = 0.f;
    int s1 = 0, s2 = 0;
#pragma unroll
    for (int q = 0; q < 4; ++q) { sce += rf[q][0]; sbn += rf[q][1]; s1 += ri[q][0]; s2 += ri[q][1]; }
    float* P = wsf + OFF_P;
    P[0 * NBLK + blk] = sce;
    P[1 * NBLK + blk] = (float)(s1 & 0xFFFF);   // hard
    P[2 * NBLK + blk] = (float)(s1 >> 16);      // hard*t
    P[3 * NBLK + blk] = (float)(s2 & 0xFFFF);   // t
    P[4 * NBLK + blk] = (float)(s2 >> 16);      // poscnt
    P[5 * NBLK + blk] = sbn;                    // boundary partial
  }

  // ---------------- last-block ticket -> finalize (replaces stage3 kernel) ----------------
  __shared__ int lastFlag;
  if (j == 0) {
    __threadfence();  // release P writes (device scope, cross-XCD via L2 wb)
    const unsigned int old = atomicAdd(wsu + OFF_TICKET, 1u);
    lastFlag = (old == NBLK - 1) ? 1 : 0;
  }
  __syncthreads();
  if (!lastFlag) return;
  __threadfence();  // acquire: all 1024 partial sets visible

  const float* P = wsf + OFF_P;
  float s0 = 0.f, s1f = 0.f, s2f = 0.f, s3f = 0.f;
#pragma unroll
  for (int k = 0; k < 4; ++k) {
    const int idx = j + (k << 8);
    s0 += P[0 * NBLK + idx];
    s1f += P[1 * NBLK + idx];
    s2f += P[2 * NBLK + idx];
    s3f += P[3 * NBLK + idx];
  }
#pragma unroll
  for (int off = 32; off > 0; off >>= 1) {
    s0 += __shfl_down(s0, off);
    s1f += __shfl_down(s1f, off);
    s2f += __shfl_down(s2f, off);
    s3f += __shfl_down(s3f, off);
  }
  __shared__ float red[4][4];
  if (lane == 0) { red[wid][0] = s0; red[wid][1] = s1f; red[wid][2] = s2f; red[wid][3] = s3f; }

  // per-sample: sample bs owns blocks [64*bs, 64*bs+64)
  const int bs = j >> 4, m = j & 15;
  float pc = 0.f, sb = 0.f;
#pragma unroll
  for (int k = 0; k < 4; ++k) {
    const int idx = (bs << 6) + m + (k << 4);
    pc += P[4 * NBLK + idx];
    sb += P[5 * NBLK + idx];
  }
  pc += __shfl_xor(pc, 1); pc += __shfl_xor(pc, 2);
  pc += __shfl_xor(pc, 4); pc += __shfl_xor(pc, 8);
  sb += __shfl_xor(sb, 1); sb += __shfl_xor(sb, 2);
  sb += __shfl_xor(sb, 4); sb += __shfl_xor(sb, 8);
  __shared__ float pcL[16], sbL[16];
  if (m == 0) { pcL[bs] = pc; sbL[bs] = sb; }
  __syncthreads();

  if (j == 0) {
    const float ceS = red[0][0] + red[1][0] + red[2][0] + red[3][0];
    const float hS  = red[0][1] + red[1][1] + red[2][1] + red[3][1];
    const float htS = red[0][2] + red[1][2] + red[2][2] + red[3][2];
    const float tS  = red[0][3] + red[1][3] + red[2][3] + red[3][3];
    const float ce = ceS * (1.0f / (float)NPIX);
    const float dice_loss = 1.0f - (2.0f * htS + 1.0f) / (hS + tS + 1.0f);
    float lb = 0.0f;
    for (int bb = 0; bb < NB; ++bb)
      lb += (pcL[bb] > 0.0f) ? sbL[bb] * (1.0f / (float)HWSZ) : 0.0f;
    out[0] = ce + dice_loss + lb * lb;
  }
}

// =====================================================================
// Fallback path: proven 3-kernel pipeline (used only if cooperative
// launch is rejected by the runtime / capture).
// =====================================================================
__global__ __launch_bounds__(256) void stage1_kernel(
    const float* __restrict__ inp, const int* __restrict__ tgt,
    unsigned int* __restrict__ wsu, float* __restrict__ wsf) {
  const int row = blockIdx.x;
  const int b = row >> 8;
  const int i = row & 255;
  const int j = threadIdx.x;

  const size_t base = (size_t)(2 * b) * HWSZ + (size_t)i * WW + j;
  const float x0 = inp[base];
  const float x1 = inp[base + HWSZ];
  const int t = tgt[(size_t)row * WW + j];

  const bool pos = x1 > x0;
  const bool hard = x1 >= x0;

  const float d = x1 - x0;
  const float ce = softplus_fast((t == 1) ? -d : d);

  __shared__ unsigned long long wsh[4];
  const unsigned long long bal = __ballot(pos);
  if ((threadIdx.x & 63) == 0) wsh[threadIdx.x >> 6] = bal;
  __syncthreads();
  unsigned long long wp[4], wn[4];
#pragma unroll
  for (int q = 0; q < 4; ++q) { wp[q] = wsh[q]; wn[q] = ~wsh[q]; }

  const int qj = j >> 6, rj = j & 63;
  const unsigned long long lowmask = (~0ull) >> (63 - rj);
  const unsigned long long himask = (~0ull) << rj;

  int loP = -(1 << 20), loN = -(1 << 20);
#pragma unroll
  for (int q = 0; q < 4; ++q) {
    unsigned long long mp = wp[q], mn = wn[q];
    if (q == qj) { mp &= lowmask; mn &= lowmask; }
    else if (q > qj) { mp = 0ull; mn = 0ull; }
    if (mp) loP = (q << 6) + 63 - __builtin_clzll(mp);
    if (mn) loN = (q << 6) + 63 - __builtin_clzll(mn);
  }
  int hiP = (1 << 20), hiN = (1 << 20);
#pragma unroll
  for (int q = 3; q >= 0; --q) {
    unsigned long long mp = wp[q], mn = wn[q];
    if (q == qj) { mp &= himask; mn &= himask; }
    else if (q < qj) { mp = 0ull; mn = 0ull; }
    if (mp) hiP = (q << 6) + (int)__builtin_ctzll(mp);
    if (mn) hiN = (q << 6) + (int)__builtin_ctzll(mn);
  }
  const int dN = min(j - loP, hiP - j);
  const int dP = min(j - loN, hiN - j);
  const unsigned int dNc = (dN > 255) ? 0xFFFFu : (unsigned int)dN;
  const unsigned int dPc = (dP > 255) ? 0xFFFFu : (unsigned int)dP;
  wsu[(size_t)row * WW + j] = dNc | (dPc << 16);

  const int tf = (t == 1) ? 1 : 0;
  float v0 = ce;
  int p1 = (hard ? 1 : 0) | ((hard && tf) ? 0x10000 : 0);
  int p2 = tf | (pos ? 0x10000 : 0);
#pragma unroll
  for (int off = 32; off > 0; off >>= 1) {
    v0 += __shfl_down(v0, off);
    p1 += __shfl_down(p1, off);
    p2 += __shfl_down(p2, off);
  }
  __shared__ float redf[4];
  __shared__ int redi[4][2];
  const int lane = threadIdx.x & 63, wid = threadIdx.x >> 6;
  if (lane == 0) { redf[wid] = v0; redi[wid][0] = p1; redi[wid][1] = p2; }
  __syncthreads();
  if (threadIdx.x == 0) {
    float sce = 0.f;
    int s1 = 0, s2 = 0;
#pragma unroll
    for (int q = 0; q < 4; ++q) { sce += redf[q]; s1 += redi[q][0]; s2 += redi[q][1]; }
    wsf[OFF_PL + 0 * ROWS + row] = sce;
    wsf[OFF_PL + 1 * ROWS + row] = (float)(s1 & 0xFFFF);
    wsf[OFF_PL + 2 * ROWS + row] = (float)(s1 >> 16);
    wsf[OFF_PL + 3 * ROWS + row] = (float)(s2 & 0xFFFF);
    wsf[OFF_PL + 4 * ROWS + row] = (float)(s2 >> 16);
  }
}

__global__ __launch_bounds__(256) void stage2_kernel(
    const int* __restrict__ tgt,
    const unsigned int* __restrict__ wsu, float* __restrict__ wsf) {
  const int row = blockIdx.x;
  const int b = row >> 8;
  const int i = row & 255;
  const int j = threadIdx.x;
  const unsigned int* g = wsu + (size_t)b * HWSZ;

  const unsigned int v0 = g[i * WW + j];
  const bool pos = (v0 & 0xFFFFu) == 0u;
  const float a0 = (float)(v0 & 0xFFFFu);
  const float b0 = (float)(v0 >> 16);
  float mN = a0 * a0;
  float mP = b0 * b0;

  const int rmax = max(i, 255 - i);
  for (int r = 1; r <= rmax; ++r) {
    const float rr = (float)(r * r);
    if (!__ballot((rr < mN) || (rr < mP))) break;
    if (i - r >= 0) {
      const unsigned int u = g[(i - r) * WW + j];
      const float a = (float)(u & 0xFFFFu);
      const float bb = (float)(u >> 16);
      mN = fminf(mN, a * a + rr);
      mP = fminf(mP, bb * bb + rr);
    }
    if (i + r < HH) {
      const unsigned int u = g[(i + r) * WW + j];
      const float a = (float)(u & 0xFFFFu);
      const float bb = (float)(u >> 16);
      mN = fminf(mN, a * a + rr);
      mP = fminf(mP, bb * bb + rr);
    }
  }

  const int t = tgt[(size_t)row * WW + j];
  const float res = pos ? (1.0f - sqrtf(mP)) : sqrtf(mN);
  float local = (t == 1) ? res : 0.0f;

#pragma unroll
  for (int off = 32; off > 0; off >>= 1) local += __shfl_down(local, off);
  __shared__ float red[4];
  const int lane = threadIdx.x & 63, wid = threadIdx.x >> 6;
  if (lane == 0) red[wid] = local;
  __syncthreads();
  if (threadIdx.x == 0)
    wsf[OFF_PART2 + row] = red[0] + red[1] + red[2] + red[3];
}

__global__ __launch_bounds__(256) void stage3_kernel(
    const float* __restrict__ wsf, float* __restrict__ out) {
  const int t = threadIdx.x;
  const float* P = wsf + OFF_PL;

  float s0 = 0.f, s1 = 0.f, s2 = 0.f, s3 = 0.f;
#pragma unroll
  for (int gi = 0; gi < 16; ++gi) {
    const int idx = t + (gi << 8);
    s0 += P[0 * ROWS + idx];
    s1 += P[1 * ROWS + idx];
    s2 += P[2 * ROWS + idx];
    s3 += P[3 * ROWS + idx];
  }
#pragma unroll
  for (int off = 32; off > 0; off >>= 1) {
    s0 += __shfl_down(s0, off);
    s1 += __shfl_down(s1, off);
    s2 += __shfl_down(s2, off);
    s3 += __shfl_down(s3, off);
  }
  __shared__ float red[4][4];
  const int lane = t & 63, wid = t >> 6;
  if (lane == 0) { red[wid][0] = s0; red[wid][1] = s1; red[wid][2] = s2; red[wid][3] = s3; }

  const int b = t >> 4, m = t & 15;
  float pc = 0.f, sb = 0.f;
#pragma unroll
  for (int k = 0; k < 16; ++k) {
    const int idx = (b << 8) + m + (k << 4);
    pc += P[4 * ROWS + idx];
    sb += wsf[OFF_PART2 + idx];
  }
  pc += __shfl_xor(pc, 1); pc += __shfl_xor(pc, 2);
  pc += __shfl_xor(pc, 4); pc += __shfl_xor(pc, 8);
  sb += __shfl_xor(sb, 1); sb += __shfl_xor(sb, 2);
  sb += __shfl_xor(sb, 4); sb += __shfl_xor(sb, 8);
  __shared__ float pcL[16], sbL[16];
  if (m == 0) { pcL[b] = pc; sbL[b] = sb; }
  __syncthreads();

  if (t == 0) {
    const float ceS = red[0][0] + red[1][0] + red[2][0] + red[3][0];
    const float hS  = red[0][1] + red[1][1] + red[2][1] + red[3][1];
    const float htS = red[0][2] + red[1][2] + red[2][2] + red[3][2];
    const float tS  = red[0][3] + red[1][3] + red[2][3] + red[3][3];
    const float ce = ceS * (1.0f / (float)NPIX);
    const float dice_loss = 1.0f - (2.0f * htS + 1.0f) / (hS + tS + 1.0f);
    float lb = 0.0f;
    for (int bb = 0; bb < NB; ++bb)
      lb += (pcL[bb] > 0.0f) ? sbL[bb] * (1.0f / (float)HWSZ) : 0.0f;
    out[0] = ce + dice_loss + lb * lb;
  }
}

extern "C" void kernel_launch(void* const* d_in, const int* in_sizes, int n_in,
                              void* d_out, int out_size, void* d_ws, size_t ws_size,
                              hipStream_t stream) {
  (void)in_sizes; (void)n_in; (void)out_size; (void)ws_size;
  const float* inp = (const float*)d_in[0];
  const int* tgt = (const int*)d_in[1];
  unsigned int* wsu = (unsigned int*)d_ws;
  float* wsf = (float*)d_ws;
  float* out = (float*)d_out;

  void* kargs[] = {(void*)&inp, (void*)&tgt, (void*)&wsu, (void*)&wsf, (void*)&out};
  hipError_t err = hipLaunchCooperativeKernel(
      (const void*)fused_kernel, dim3(NBLK), dim3(256), kargs, 0, stream);
  if (err != hipSuccess) {
    // Fallback: proven 3-kernel pipeline (no atomics, no memset needed).
    stage1_kernel<<<ROWS, 256, 0, stream>>>(inp, tgt, wsu, wsf);
    stage2_kernel<<<ROWS, 256, 0, stream>>>(tgt, wsu, wsf);
    stage3_kernel<<<1, 256, 0, stream>>>(wsf, out);
  }
}

// Round 2
// 161.426 us; speedup vs baseline: 1.0563x; 1.0563x over previous
//
#include <hip/hip_runtime.h>

#define NB 16
#define HH 256
#define WW 256
#define HWSZ (HH * WW)
#define NPIX (NB * HWSZ)
#define ROWS (NB * HH)  // 4096

// ws layout (4-byte units):
//   [0, NPIX)                 packed u16 pair per pixel: lo=dN (dist to nearest pos), hi=dP (to nearest neg)
//   [NPIX + v*ROWS + row]     P[v][row], v=0..4: per-row partials {ce, hard, hard*t, t, poscnt}
//   [NPIX + 5*ROWS + row]     part2[row]: per-row boundary sum
//   [NPIX + 6*ROWS]           ticket counter (u32), zeroed by stage1 block 0
#define OFF_P NPIX
#define OFF_PART2 (NPIX + 5 * ROWS)
#define OFF_TICKET (NPIX + 6 * ROWS)

#define LOG2E 1.44269504088896340736f
#define LN2 0.69314718055994530942f

// softplus(z) = log(1+e^z) = max(z,0) + ln2*log2(1+exp2(-|z|*log2e))
__device__ __forceinline__ float softplus_fast(float z) {
  const float u = __builtin_amdgcn_exp2f(-fabsf(z) * LOG2E);
  return fmaxf(z, 0.0f) + LN2 * __builtin_amdgcn_logf(1.0f + u);
}

// ---------------- Stage 1: wave-per-row CE/dice partials + 1D row EDT ----------------
// Block = 256 threads = 4 waves = 4 rows. Lane l of a wave owns pixels
// {l, l+64, l+128, l+192} of its row, so the 4 __ballot results ARE the
// row's contiguous 256-bit pos-mask (word q = pixels [64q, 64q+64)).
// No __syncthreads, no LDS: ballots + shfl reductions are wave-local.
__global__ __launch_bounds__(256) void stage1_kernel(
    const float* __restrict__ inp, const int* __restrict__ tgt,
    unsigned int* __restrict__ wsu, float* __restrict__ wsf) {
  const int wid = threadIdx.x >> 6;
  const int lane = threadIdx.x & 63;
  const int row = (blockIdx.x << 2) + wid;  // grid = 1024 blocks
  const int b = row >> 8;
  const int i = row & 255;

  if (blockIdx.x == 0 && threadIdx.x == 0) wsu[OFF_TICKET] = 0u;

  const size_t ibase = (size_t)(2 * b) * HWSZ + (size_t)i * WW;
  const size_t tbase = (size_t)row * WW;

  float x0[4], x1[4];
  int t[4];
#pragma unroll
  for (int q = 0; q < 4; ++q) {
    const int p = (q << 6) + lane;
    x0[q] = inp[ibase + p];
    x1[q] = inp[ibase + HWSZ + p];
    t[q] = tgt[tbase + p];
  }

  unsigned long long wp[4], wn[4];
  float ceAcc = 0.0f;
  int p1 = 0, p2 = 0;  // packed 16-bit fields; per-row sums <= 256: no carry
#pragma unroll
  for (int q = 0; q < 4; ++q) {
    const bool pos = x1[q] > x0[q];    // argmax==1 (ties -> class 0)
    const bool hard = x1[q] >= x0[q];  // probs1 >= 0.5
    const bool tf = (t[q] == 1);
    const float d = x1[q] - x0[q];
    ceAcc += softplus_fast(tf ? -d : d);
    p1 += (hard ? 1 : 0) | ((hard && tf) ? 0x10000 : 0);
    p2 += (tf ? 1 : 0) | (pos ? 0x10000 : 0);
    wp[q] = __ballot(pos);
    wn[q] = ~wp[q];
  }

  const unsigned long long lowmask = (~0ull) >> (63 - lane);
  const unsigned long long himask = (~0ull) << lane;
#pragma unroll
  for (int q = 0; q < 4; ++q) {
    int loP = -(1 << 20), loN = -(1 << 20);
#pragma unroll
    for (int u = 0; u < 4; ++u) {
      unsigned long long mp = wp[u], mn = wn[u];
      if (u == q) { mp &= lowmask; mn &= lowmask; }
      else if (u > q) { mp = 0ull; mn = 0ull; }
      if (mp) loP = (u << 6) + 63 - __builtin_clzll(mp);
      if (mn) loN = (u << 6) + 63 - __builtin_clzll(mn);
    }
    int hiP = (1 << 20), hiN = (1 << 20);
#pragma unroll
    for (int u = 3; u >= 0; --u) {
      unsigned long long mp = wp[u], mn = wn[u];
      if (u == q) { mp &= himask; mn &= himask; }
      else if (u < q) { mp = 0ull; mn = 0ull; }
      if (mp) hiP = (u << 6) + (int)__builtin_ctzll(mp);
      if (mn) hiN = (u << 6) + (int)__builtin_ctzll(mn);
    }
    const int p = (q << 6) + lane;
    const int dN = min(p - loP, hiP - p);  // dist to nearest pos pixel in row
    const int dP = min(p - loN, hiN - p);  // dist to nearest neg pixel in row
    const unsigned int dNc = (dN > 255) ? 0xFFFFu : (unsigned int)dN;
    const unsigned int dPc = (dP > 255) ? 0xFFFFu : (unsigned int)dP;
    wsu[tbase + p] = dNc | (dPc << 16);
  }

  // Wave-local reduction (row == wave), no barriers
#pragma unroll
  for (int off = 32; off > 0; off >>= 1) {
    ceAcc += __shfl_down(ceAcc, off);
    p1 += __shfl_down(p1, off);
    p2 += __shfl_down(p2, off);
  }
  if (lane == 0) {
    wsf[OFF_P + 0 * ROWS + row] = ceAcc;
    wsf[OFF_P + 1 * ROWS + row] = (float)(p1 & 0xFFFF);
    wsf[OFF_P + 2 * ROWS + row] = (float)(p1 >> 16);
    wsf[OFF_P + 3 * ROWS + row] = (float)(p2 & 0xFFFF);
    wsf[OFF_P + 4 * ROWS + row] = (float)(p2 >> 16);
  }
}

// ---------------- Stage 2: windowed exact column EDT + boundary partial
//                  + last-block ticket finalize (old stage3 folded in) ----------------
__global__ __launch_bounds__(256) void stage2_kernel(
    const int* __restrict__ tgt,
    unsigned int* __restrict__ wsu, float* __restrict__ wsf,
    float* __restrict__ out) {
  const int row = blockIdx.x;
  const int b = row >> 8;
  const int i = row & 255;
  const int j = threadIdx.x;
  const unsigned int* g = wsu + (size_t)b * HWSZ;

  // r = 0 candidate; pos <=> dN == 0 (no inp re-read needed)
  const unsigned int v0 = g[i * WW + j];
  // Unconditional prefetch r=1,2: 4 independent loads in flight (vs serial
  // load->ballot->branch per radius). 0xFFFFFFFF decodes to (65535,65535):
  // candidates ~4.3e9 never lower the running min -> harmless neutral.
  unsigned int uA = 0xFFFFFFFFu, uB = 0xFFFFFFFFu, uC = 0xFFFFFFFFu, uD = 0xFFFFFFFFu;
  if (i - 1 >= 0) uA = g[(i - 1) * WW + j];
  if (i + 1 < HH) uB = g[(i + 1) * WW + j];
  if (i - 2 >= 0) uC = g[(i - 2) * WW + j];
  if (i + 2 < HH) uD = g[(i + 2) * WW + j];

  const bool pos = (v0 & 0xFFFFu) == 0u;
  const float a0 = (float)(v0 & 0xFFFFu);
  const float b0 = (float)(v0 >> 16);
  float mN = a0 * a0;  // running min for dn^2 (edt of neg mask: zeros at pos pixels)
  float mP = b0 * b0;  // running min for dp^2

  {
    float a, bb;
    a = (float)(uA & 0xFFFFu); bb = (float)(uA >> 16);
    mN = fminf(mN, a * a + 1.0f); mP = fminf(mP, bb * bb + 1.0f);
    a = (float)(uB & 0xFFFFu); bb = (float)(uB >> 16);
    mN = fminf(mN, a * a + 1.0f); mP = fminf(mP, bb * bb + 1.0f);
    a = (float)(uC & 0xFFFFu); bb = (float)(uC >> 16);
    mN = fminf(mN, a * a + 4.0f); mP = fminf(mP, bb * bb + 4.0f);
    a = (float)(uD & 0xFFFFu); bb = (float)(uD >> 16);
    mN = fminf(mN, a * a + 4.0f); mP = fminf(mP, bb * bb + 4.0f);
  }

  // Outward exact search from r=3: any skipped k has (i-k)^2 >= r^2 >= current min
  const int rmax = max(i, 255 - i);
  for (int r = 3; r <= rmax; ++r) {
    const float rr = (float)(r * r);
    if (!__ballot((rr < mN) || (rr < mP))) break;  // whole wave done
    if (i - r >= 0) {
      const unsigned int u = g[(i - r) * WW + j];
      const float a = (float)(u & 0xFFFFu);
      const float bb = (float)(u >> 16);
      mN = fminf(mN, a * a + rr);
      mP = fminf(mP, bb * bb + rr);
    }
    if (i + r < HH) {
      const unsigned int u = g[(i + r) * WW + j];
      const float a = (float)(u & 0xFFFFu);
      const float bb = (float)(u >> 16);
      mN = fminf(mN, a * a + rr);
      mP = fminf(mP, bb * bb + rr);
    }
  }

  const int t = tgt[(size_t)row * WW + j];
  // res = dn*neg - (dp-1)*pos
  const float res = pos ? (1.0f - sqrtf(mP)) : sqrtf(mN);
  float local = (t == 1) ? res : 0.0f;

#pragma unroll
  for (int off = 32; off > 0; off >>= 1) local += __shfl_down(local, off);
  __shared__ float red2[4];
  const int lane = threadIdx.x & 63, wid = threadIdx.x >> 6;
  if (lane == 0) red2[wid] = local;
  __syncthreads();

  // ---- ticket: last block to finish does the scalar finalize ----
  __shared__ int lastFlag;
  if (threadIdx.x == 0) {
    wsf[OFF_PART2 + row] = red2[0] + red2[1] + red2[2] + red2[3];
    __threadfence();  // release this block's partial before the ticket bump
    const unsigned int old = atomicAdd(wsu + OFF_TICKET, 1u);
    lastFlag = (old == ROWS - 1) ? 1 : 0;
  }
  __syncthreads();
  if (!lastFlag) return;
  __threadfence();  // acquire: all 4096 partials (+ stage1's P) visible

  // ---------------- finalize (old stage3 body) ----------------
  const float* P = wsf + OFF_P;
  const int tt = threadIdx.x;

  float s0 = 0.f, s1 = 0.f, s2 = 0.f, s3 = 0.f;
#pragma unroll
  for (int gi = 0; gi < 16; ++gi) {
    const int idx = tt + (gi << 8);
    s0 += P[0 * ROWS + idx];
    s1 += P[1 * ROWS + idx];
    s2 += P[2 * ROWS + idx];
    s3 += P[3 * ROWS + idx];
  }
#pragma unroll
  for (int off = 32; off > 0; off >>= 1) {
    s0 += __shfl_down(s0, off);
    s1 += __shfl_down(s1, off);
    s2 += __shfl_down(s2, off);
    s3 += __shfl_down(s3, off);
  }
  __shared__ float red[4][4];
  if (lane == 0) { red[wid][0] = s0; red[wid][1] = s1; red[wid][2] = s2; red[wid][3] = s3; }

  // Per-sample sums: thread tt -> sample bs=tt>>4, slot m=tt&15, each sums 16 rows
  const int bs = tt >> 4, m = tt & 15;
  float pc = 0.f, sb = 0.f;
#pragma unroll
  for (int k = 0; k < 16; ++k) {
    const int idx = (bs << 8) + m + (k << 4);
    pc += P[4 * ROWS + idx];
    sb += wsf[OFF_PART2 + idx];
  }
  pc += __shfl_xor(pc, 1); pc += __shfl_xor(pc, 2);
  pc += __shfl_xor(pc, 4); pc += __shfl_xor(pc, 8);
  sb += __shfl_xor(sb, 1); sb += __shfl_xor(sb, 2);
  sb += __shfl_xor(sb, 4); sb += __shfl_xor(sb, 8);
  __shared__ float pcL[16], sbL[16];
  if (m == 0) { pcL[bs] = pc; sbL[bs] = sb; }
  __syncthreads();

  if (tt == 0) {
    const float ceS = red[0][0] + red[1][0] + red[2][0] + red[3][0];
    const float hS  = red[0][1] + red[1][1] + red[2][1] + red[3][1];
    const float htS = red[0][2] + red[1][2] + red[2][2] + red[3][2];
    const float tS  = red[0][3] + red[1][3] + red[2][3] + red[3][3];
    const float ce = ceS * (1.0f / (float)NPIX);
    const float dice_loss = 1.0f - (2.0f * htS + 1.0f) / (hS + tS + 1.0f);
    float lb = 0.0f;
    for (int bb = 0; bb < NB; ++bb)
      lb += (pcL[bb] > 0.0f) ? sbL[bb] * (1.0f / (float)HWSZ) : 0.0f;
    out[0] = ce + dice_loss + lb * lb;
  }
}

extern "C" void kernel_launch(void* const* d_in, const int* in_sizes, int n_in,
                              void* d_out, int out_size, void* d_ws, size_t ws_size,
                              hipStream_t stream) {
  (void)in_sizes; (void)n_in; (void)out_size; (void)ws_size;
  const float* inp = (const float*)d_in[0];
  const int* tgt = (const int*)d_in[1];
  // d_in[2] starget, d_in[3] dice_co, d_in[4] boundary_co: unused by reference
  unsigned int* wsu = (unsigned int*)d_ws;
  float* wsf = (float*)d_ws;
  float* out = (float*)d_out;

  // 2 dispatches. stage1 zeroes the ticket; stage2's last block finalizes.
  stage1_kernel<<<ROWS / 4, 256, 0, stream>>>(inp, tgt, wsu, wsf);
  stage2_kernel<<<ROWS, 256, 0, stream>>>(tgt, wsu, wsf, out);
}

// Round 3
// 81.359 us; speedup vs baseline: 2.0959x; 1.9841x over previous
//
#include <hip/hip_runtime.h>

#define NB 16
#define HH 256
#define WW 256
#define HWSZ (HH * WW)
#define NPIX (NB * HWSZ)
#define ROWS (NB * HH)  // 4096

// ws layout (4-byte units):
//   [0, NPIX)                 packed u16 pair per pixel: lo=dN (dist to nearest pos), hi=dP (to nearest neg)
//   [NPIX + v*ROWS + row]     P[v][row], v=0..4: per-row partials {ce, hard, hard*t, t, poscnt}
//   [NPIX + 5*ROWS + row]     part2[row]: per-row boundary sum
// No atomics / fences / tickets anywhere: kernel boundaries provide coherence.
#define OFF_P NPIX
#define OFF_PART2 (NPIX + 5 * ROWS)

#define LOG2E 1.44269504088896340736f
#define LN2 0.69314718055994530942f

// softplus(z) = log(1+e^z) = max(z,0) + ln2*log2(1+exp2(-|z|*log2e))
__device__ __forceinline__ float softplus_fast(float z) {
  const float u = __builtin_amdgcn_exp2f(-fabsf(z) * LOG2E);
  return fmaxf(z, 0.0f) + LN2 * __builtin_amdgcn_logf(1.0f + u);
}

// ---------------- Stage 1: wave-per-row CE/dice partials + 1D row EDT ----------------
// Block = 256 threads = 4 waves = 4 rows. Lane l of a wave owns pixels
// {l, l+64, l+128, l+192} of its row, so the 4 __ballot results ARE the
// row's contiguous 256-bit pos-mask (word q = pixels [64q, 64q+64)).
// No __syncthreads, no LDS: ballots + shfl reductions are wave-local.
__global__ __launch_bounds__(256) void stage1_kernel(
    const float* __restrict__ inp, const int* __restrict__ tgt,
    unsigned int* __restrict__ wsu, float* __restrict__ wsf) {
  const int wid = threadIdx.x >> 6;
  const int lane = threadIdx.x & 63;
  const int row = (blockIdx.x << 2) + wid;  // grid = 1024 blocks
  const int b = row >> 8;
  const int i = row & 255;

  const size_t ibase = (size_t)(2 * b) * HWSZ + (size_t)i * WW;
  const size_t tbase = (size_t)row * WW;

  float x0[4], x1[4];
  int t[4];
#pragma unroll
  for (int q = 0; q < 4; ++q) {
    const int p = (q << 6) + lane;
    x0[q] = inp[ibase + p];
    x1[q] = inp[ibase + HWSZ + p];
    t[q] = tgt[tbase + p];
  }

  unsigned long long wp[4], wn[4];
  float ceAcc = 0.0f;
  int p1 = 0, p2 = 0;  // packed 16-bit fields; per-row sums <= 256: no carry
#pragma unroll
  for (int q = 0; q < 4; ++q) {
    const bool pos = x1[q] > x0[q];    // argmax==1 (ties -> class 0)
    const bool hard = x1[q] >= x0[q];  // probs1 >= 0.5
    const bool tf = (t[q] == 1);
    const float d = x1[q] - x0[q];
    ceAcc += softplus_fast(tf ? -d : d);
    p1 += (hard ? 1 : 0) | ((hard && tf) ? 0x10000 : 0);
    p2 += (tf ? 1 : 0) | (pos ? 0x10000 : 0);
    wp[q] = __ballot(pos);
    wn[q] = ~wp[q];
  }

  const unsigned long long lowmask = (~0ull) >> (63 - lane);
  const unsigned long long himask = (~0ull) << lane;
#pragma unroll
  for (int q = 0; q < 4; ++q) {
    int loP = -(1 << 20), loN = -(1 << 20);
#pragma unroll
    for (int u = 0; u < 4; ++u) {
      unsigned long long mp = wp[u], mn = wn[u];
      if (u == q) { mp &= lowmask; mn &= lowmask; }
      else if (u > q) { mp = 0ull; mn = 0ull; }
      if (mp) loP = (u << 6) + 63 - __builtin_clzll(mp);
      if (mn) loN = (u << 6) + 63 - __builtin_clzll(mn);
    }
    int hiP = (1 << 20), hiN = (1 << 20);
#pragma unroll
    for (int u = 3; u >= 0; --u) {
      unsigned long long mp = wp[u], mn = wn[u];
      if (u == q) { mp &= himask; mn &= himask; }
      else if (u < q) { mp = 0ull; mn = 0ull; }
      if (mp) hiP = (u << 6) + (int)__builtin_ctzll(mp);
      if (mn) hiN = (u << 6) + (int)__builtin_ctzll(mn);
    }
    const int p = (q << 6) + lane;
    const int dN = min(p - loP, hiP - p);  // dist to nearest pos pixel in row
    const int dP = min(p - loN, hiN - p);  // dist to nearest neg pixel in row
    const unsigned int dNc = (dN > 255) ? 0xFFFFu : (unsigned int)dN;
    const unsigned int dPc = (dP > 255) ? 0xFFFFu : (unsigned int)dP;
    wsu[tbase + p] = dNc | (dPc << 16);
  }

  // Wave-local reduction (row == wave), no barriers
#pragma unroll
  for (int off = 32; off > 0; off >>= 1) {
    ceAcc += __shfl_down(ceAcc, off);
    p1 += __shfl_down(p1, off);
    p2 += __shfl_down(p2, off);
  }
  if (lane == 0) {
    wsf[OFF_P + 0 * ROWS + row] = ceAcc;
    wsf[OFF_P + 1 * ROWS + row] = (float)(p1 & 0xFFFF);
    wsf[OFF_P + 2 * ROWS + row] = (float)(p1 >> 16);
    wsf[OFF_P + 3 * ROWS + row] = (float)(p2 & 0xFFFF);
    wsf[OFF_P + 4 * ROWS + row] = (float)(p2 >> 16);
  }
}

// ---------------- Stage 2: windowed exact column EDT + boundary partial ----------------
__global__ __launch_bounds__(256) void stage2_kernel(
    const int* __restrict__ tgt,
    const unsigned int* __restrict__ wsu, float* __restrict__ wsf) {
  const int row = blockIdx.x;
  const int b = row >> 8;
  const int i = row & 255;
  const int j = threadIdx.x;
  const unsigned int* g = wsu + (size_t)b * HWSZ;

  // r = 0 candidate; pos <=> dN == 0 (no inp re-read needed)
  const unsigned int v0 = g[i * WW + j];
  // Unconditional prefetch r=1,2: 4 independent loads in flight (vs serial
  // load->ballot->branch per radius). 0xFFFFFFFF decodes to (65535,65535):
  // candidates ~4.3e9 never lower the running min -> harmless neutral.
  unsigned int uA = 0xFFFFFFFFu, uB = 0xFFFFFFFFu, uC = 0xFFFFFFFFu, uD = 0xFFFFFFFFu;
  if (i - 1 >= 0) uA = g[(i - 1) * WW + j];
  if (i + 1 < HH) uB = g[(i + 1) * WW + j];
  if (i - 2 >= 0) uC = g[(i - 2) * WW + j];
  if (i + 2 < HH) uD = g[(i + 2) * WW + j];

  const bool pos = (v0 & 0xFFFFu) == 0u;
  const float a0 = (float)(v0 & 0xFFFFu);
  const float b0 = (float)(v0 >> 16);
  float mN = a0 * a0;  // running min for dn^2 (edt of neg mask: zeros at pos pixels)
  float mP = b0 * b0;  // running min for dp^2

  {
    float a, bb;
    a = (float)(uA & 0xFFFFu); bb = (float)(uA >> 16);
    mN = fminf(mN, a * a + 1.0f); mP = fminf(mP, bb * bb + 1.0f);
    a = (float)(uB & 0xFFFFu); bb = (float)(uB >> 16);
    mN = fminf(mN, a * a + 1.0f); mP = fminf(mP, bb * bb + 1.0f);
    a = (float)(uC & 0xFFFFu); bb = (float)(uC >> 16);
    mN = fminf(mN, a * a + 4.0f); mP = fminf(mP, bb * bb + 4.0f);
    a = (float)(uD & 0xFFFFu); bb = (float)(uD >> 16);
    mN = fminf(mN, a * a + 4.0f); mP = fminf(mP, bb * bb + 4.0f);
  }

  // Outward exact search from r=3: any skipped k has (i-k)^2 >= r^2 >= current min
  const int rmax = max(i, 255 - i);
  for (int r = 3; r <= rmax; ++r) {
    const float rr = (float)(r * r);
    if (!__ballot((rr < mN) || (rr < mP))) break;  // whole wave done
    if (i - r >= 0) {
      const unsigned int u = g[(i - r) * WW + j];
      const float a = (float)(u & 0xFFFFu);
      const float bb = (float)(u >> 16);
      mN = fminf(mN, a * a + rr);
      mP = fminf(mP, bb * bb + rr);
    }
    if (i + r < HH) {
      const unsigned int u = g[(i + r) * WW + j];
      const float a = (float)(u & 0xFFFFu);
      const float bb = (float)(u >> 16);
      mN = fminf(mN, a * a + rr);
      mP = fminf(mP, bb * bb + rr);
    }
  }

  const int t = tgt[(size_t)row * WW + j];
  // res = dn*neg - (dp-1)*pos
  const float res = pos ? (1.0f - sqrtf(mP)) : sqrtf(mN);
  float local = (t == 1) ? res : 0.0f;

#pragma unroll
  for (int off = 32; off > 0; off >>= 1) local += __shfl_down(local, off);
  __shared__ float red[4];
  const int lane = threadIdx.x & 63, wid = threadIdx.x >> 6;
  if (lane == 0) red[wid] = local;
  __syncthreads();
  if (threadIdx.x == 0)
    wsf[OFF_PART2 + row] = red[0] + red[1] + red[2] + red[3];
}

// ---------------- Stage 3: reduce all partials + finalize scalar ----------------
__global__ __launch_bounds__(256) void stage3_kernel(
    const float* __restrict__ wsf, float* __restrict__ out) {
  const int t = threadIdx.x;
  const float* P = wsf + OFF_P;

  // Global sums over 4096 rows for v=0..3
  float s0 = 0.f, s1 = 0.f, s2 = 0.f, s3 = 0.f;
#pragma unroll
  for (int gi = 0; gi < 16; ++gi) {
    const int idx = t + (gi << 8);
    s0 += P[0 * ROWS + idx];
    s1 += P[1 * ROWS + idx];
    s2 += P[2 * ROWS + idx];
    s3 += P[3 * ROWS + idx];
  }
#pragma unroll
  for (int off = 32; off > 0; off >>= 1) {
    s0 += __shfl_down(s0, off);
    s1 += __shfl_down(s1, off);
    s2 += __shfl_down(s2, off);
    s3 += __shfl_down(s3, off);
  }
  __shared__ float red[4][4];
  const int lane = t & 63, wid = t >> 6;
  if (lane == 0) { red[wid][0] = s0; red[wid][1] = s1; red[wid][2] = s2; red[wid][3] = s3; }

  // Per-sample sums: thread t -> sample b=t>>4, slot m=t&15, each sums 16 rows
  const int b = t >> 4, m = t & 15;
  float pc = 0.f, sb = 0.f;
#pragma unroll
  for (int k = 0; k < 16; ++k) {
    const int idx = (b << 8) + m + (k << 4);
    pc += P[4 * ROWS + idx];
    sb += wsf[OFF_PART2 + idx];
  }
  pc += __shfl_xor(pc, 1); pc += __shfl_xor(pc, 2);
  pc += __shfl_xor(pc, 4); pc += __shfl_xor(pc, 8);
  sb += __shfl_xor(sb, 1); sb += __shfl_xor(sb, 2);
  sb += __shfl_xor(sb, 4); sb += __shfl_xor(sb, 8);
  __shared__ float pcL[16], sbL[16];
  if (m == 0) { pcL[b] = pc; sbL[b] = sb; }
  __syncthreads();

  if (t == 0) {
    const float ceS = red[0][0] + red[1][0] + red[2][0] + red[3][0];
    const float hS  = red[0][1] + red[1][1] + red[2][1] + red[3][1];
    const float htS = red[0][2] + red[1][2] + red[2][2] + red[3][2];
    const float tS  = red[0][3] + red[1][3] + red[2][3] + red[3][3];
    const float ce = ceS * (1.0f / (float)NPIX);
    const float dice_loss = 1.0f - (2.0f * htS + 1.0f) / (hS + tS + 1.0f);
    float lb = 0.0f;
    for (int bb = 0; bb < NB; ++bb)
      lb += (pcL[bb] > 0.0f) ? sbL[bb] * (1.0f / (float)HWSZ) : 0.0f;
    out[0] = ce + dice_loss + lb * lb;
  }
}

extern "C" void kernel_launch(void* const* d_in, const int* in_sizes, int n_in,
                              void* d_out, int out_size, void* d_ws, size_t ws_size,
                              hipStream_t stream) {
  (void)in_sizes; (void)n_in; (void)out_size; (void)ws_size;
  const float* inp = (const float*)d_in[0];
  const int* tgt = (const int*)d_in[1];
  // d_in[2] starget, d_in[3] dice_co, d_in[4] boundary_co: unused by reference
  unsigned int* wsu = (unsigned int*)d_ws;
  float* wsf = (float*)d_ws;
  float* out = (float*)d_out;

  // No atomics anywhere -> no memset needed; all partial slots are fully overwritten.
  // Kernel boundaries (graph edges) are the cheap coherence mechanism on this
  // runtime; grid.sync / fence+ticket measured 10-30x worse (rounds 1-2).
  stage1_kernel<<<ROWS / 4, 256, 0, stream>>>(inp, tgt, wsu, wsf);
  stage2_kernel<<<ROWS, 256, 0, stream>>>(tgt, wsu, wsf);
  stage3_kernel<<<1, 256, 0, stream>>>(wsf, out);
}

// Round 4
// 80.123 us; speedup vs baseline: 2.1282x; 1.0154x over previous
//
#include <hip/hip_runtime.h>

#define NB 16
#define HH 256
#define WW 256
#define HWSZ (HH * WW)
#define NPIX (NB * HWSZ)
#define ROWS (NB * HH)  // 4096

// ws layout (4-byte units):
//   [0, NPIX)                 packed per pixel: bits0-8 dN (9b, sentinel 0x1FF),
//                             bit15 t-flag (tgt==1), bits16-24 dP (9b, sentinel 0x1FF)
//   [NPIX + v*ROWS + row]     P[v][row], v=0..4: per-row partials {ce, hard, hard*t, t, poscnt}
//   [NPIX + 5*ROWS + row]     part2[row]: per-row boundary sum
// No atomics / fences / tickets anywhere: kernel boundaries provide coherence
// (grid.sync / fence+ticket measured 10-30x worse on this runtime, rounds 1-2).
#define OFF_P NPIX
#define OFF_PART2 (NPIX + 5 * ROWS)

#define LOG2E 1.44269504088896340736f
#define LN2 0.69314718055994530942f

// softplus(z) = log(1+e^z) = max(z,0) + ln2*log2(1+exp2(-|z|*log2e))
__device__ __forceinline__ float softplus_fast(float z) {
  const float u = __builtin_amdgcn_exp2f(-fabsf(z) * LOG2E);
  return fmaxf(z, 0.0f) + LN2 * __builtin_amdgcn_logf(1.0f + u);
}

// ---------------- Stage 1: wave-per-row CE/dice partials + 1D row EDT ----------------
// Block = 256 threads = 4 waves = 4 rows. Lane l of a wave owns pixels
// {l, l+64, l+128, l+192} of its row, so the 4 __ballot results ARE the
// row's contiguous 256-bit pos-mask (word q = pixels [64q, 64q+64)).
// No __syncthreads, no LDS: ballots + shfl reductions are wave-local.
__global__ __launch_bounds__(256) void stage1_kernel(
    const float* __restrict__ inp, const int* __restrict__ tgt,
    unsigned int* __restrict__ wsu, float* __restrict__ wsf) {
  const int wid = threadIdx.x >> 6;
  const int lane = threadIdx.x & 63;
  const int row = (blockIdx.x << 2) + wid;  // grid = 1024 blocks
  const int b = row >> 8;
  const int i = row & 255;

  const size_t ibase = (size_t)(2 * b) * HWSZ + (size_t)i * WW;
  const size_t tbase = (size_t)row * WW;

  float x0[4], x1[4];
  int t[4];
#pragma unroll
  for (int q = 0; q < 4; ++q) {
    const int p = (q << 6) + lane;
    x0[q] = inp[ibase + p];
    x1[q] = inp[ibase + HWSZ + p];
    t[q] = tgt[tbase + p];
  }

  unsigned long long wp[4], wn[4];
  float ceAcc = 0.0f;
  int p1 = 0, p2 = 0;  // packed 16-bit fields; per-row sums <= 256: no carry
#pragma unroll
  for (int q = 0; q < 4; ++q) {
    const bool pos = x1[q] > x0[q];    // argmax==1 (ties -> class 0)
    const bool hard = x1[q] >= x0[q];  // probs1 >= 0.5
    const bool tf = (t[q] == 1);
    const float d = x1[q] - x0[q];
    ceAcc += softplus_fast(tf ? -d : d);
    p1 += (hard ? 1 : 0) | ((hard && tf) ? 0x10000 : 0);
    p2 += (tf ? 1 : 0) | (pos ? 0x10000 : 0);
    wp[q] = __ballot(pos);
    wn[q] = ~wp[q];
  }

  const unsigned long long lowmask = (~0ull) >> (63 - lane);
  const unsigned long long himask = (~0ull) << lane;
#pragma unroll
  for (int q = 0; q < 4; ++q) {
    int loP = -(1 << 20), loN = -(1 << 20);
#pragma unroll
    for (int u = 0; u < 4; ++u) {
      unsigned long long mp = wp[u], mn = wn[u];
      if (u == q) { mp &= lowmask; mn &= lowmask; }
      else if (u > q) { mp = 0ull; mn = 0ull; }
      if (mp) loP = (u << 6) + 63 - __builtin_clzll(mp);
      if (mn) loN = (u << 6) + 63 - __builtin_clzll(mn);
    }
    int hiP = (1 << 20), hiN = (1 << 20);
#pragma unroll
    for (int u = 3; u >= 0; --u) {
      unsigned long long mp = wp[u], mn = wn[u];
      if (u == q) { mp &= himask; mn &= himask; }
      else if (u < q) { mp = 0ull; mn = 0ull; }
      if (mp) hiP = (u << 6) + (int)__builtin_ctzll(mp);
      if (mn) hiN = (u << 6) + (int)__builtin_ctzll(mn);
    }
    const int p = (q << 6) + lane;
    const int dN = min(p - loP, hiP - p);  // dist to nearest pos pixel in row
    const int dP = min(p - loN, hiN - p);  // dist to nearest neg pixel in row
    // 9-bit fields, sentinel 0x1FF (511; 511^2=261121 > max true d^2=130050
    // -> always neutral in the running min). t-flag in bit 15.
    const unsigned int dNc = (dN > 255) ? 0x1FFu : (unsigned int)dN;
    const unsigned int dPc = (dP > 255) ? 0x1FFu : (unsigned int)dP;
    const unsigned int tb = (t[q] == 1) ? 0x8000u : 0u;
    wsu[tbase + p] = dNc | tb | (dPc << 16);
  }

  // Wave-local reduction (row == wave), no barriers
#pragma unroll
  for (int off = 32; off > 0; off >>= 1) {
    ceAcc += __shfl_down(ceAcc, off);
    p1 += __shfl_down(p1, off);
    p2 += __shfl_down(p2, off);
  }
  if (lane == 0) {
    wsf[OFF_P + 0 * ROWS + row] = ceAcc;
    wsf[OFF_P + 1 * ROWS + row] = (float)(p1 & 0xFFFF);
    wsf[OFF_P + 2 * ROWS + row] = (float)(p1 >> 16);
    wsf[OFF_P + 3 * ROWS + row] = (float)(p2 & 0xFFFF);
    wsf[OFF_P + 4 * ROWS + row] = (float)(p2 >> 16);
  }
}

// ---------------- Stage 2: windowed exact column EDT + boundary partial ----------------
__global__ __launch_bounds__(256) void stage2_kernel(
    const unsigned int* __restrict__ wsu, float* __restrict__ wsf) {
  // XCD-chunked swizzle: consecutive blockIdx round-robin across 8 XCDs, so
  // (bid&7) = XCD id. Give each XCD 512 consecutive rows (= 2 samples,
  // ~0.5 MB of wsu) so the +-r neighborhood reads are same-L2 hits instead
  // of scattering across 8 non-coherent L2s. Bijective: 4096 = 8*512.
  const int bid = blockIdx.x;
  const int row = ((bid & 7) << 9) | (bid >> 3);
  const int b = row >> 8;
  const int i = row & 255;
  const int j = threadIdx.x;
  const unsigned int* g = wsu + (size_t)b * HWSZ;

  // r = 0 candidate; pos <=> dN == 0 (no inp re-read needed)
  const unsigned int v0 = g[i * WW + j];
  // Unconditional prefetch r=1,2: 4 independent loads in flight (vs serial
  // load->ballot->branch per radius). 0x01FF01FF decodes to (511,511):
  // sentinel candidates never lower the running min -> harmless neutral.
  unsigned int uA = 0x01FF01FFu, uB = 0x01FF01FFu, uC = 0x01FF01FFu, uD = 0x01FF01FFu;
  if (i - 1 >= 0) uA = g[(i - 1) * WW + j];
  if (i + 1 < HH) uB = g[(i + 1) * WW + j];
  if (i - 2 >= 0) uC = g[(i - 2) * WW + j];
  if (i + 2 < HH) uD = g[(i + 2) * WW + j];

  const bool pos = (v0 & 0x1FFu) == 0u;
  const bool tf = (v0 & 0x8000u) != 0u;  // tgt==1, packed by stage1
  const float a0 = (float)(v0 & 0x1FFu);
  const float b0 = (float)(v0 >> 16);
  float mN = a0 * a0;  // running min for dn^2 (edt of neg mask: zeros at pos pixels)
  float mP = b0 * b0;  // running min for dp^2

  {
    float a, bb;
    a = (float)(uA & 0x1FFu); bb = (float)(uA >> 16);
    mN = fminf(mN, a * a + 1.0f); mP = fminf(mP, bb * bb + 1.0f);
    a = (float)(uB & 0x1FFu); bb = (float)(uB >> 16);
    mN = fminf(mN, a * a + 1.0f); mP = fminf(mP, bb * bb + 1.0f);
    a = (float)(uC & 0x1FFu); bb = (float)(uC >> 16);
    mN = fminf(mN, a * a + 4.0f); mP = fminf(mP, bb * bb + 4.0f);
    a = (float)(uD & 0x1FFu); bb = (float)(uD >> 16);
    mN = fminf(mN, a * a + 4.0f); mP = fminf(mP, bb * bb + 4.0f);
  }

  // Outward exact search from r=3: any skipped k has (i-k)^2 >= r^2 >= current min
  const int rmax = max(i, 255 - i);
  for (int r = 3; r <= rmax; ++r) {
    const float rr = (float)(r * r);
    if (!__ballot((rr < mN) || (rr < mP))) break;  // whole wave done
    if (i - r >= 0) {
      const unsigned int u = g[(i - r) * WW + j];
      const float a = (float)(u & 0x1FFu);
      const float bb = (float)(u >> 16);
      mN = fminf(mN, a * a + rr);
      mP = fminf(mP, bb * bb + rr);
    }
    if (i + r < HH) {
      const unsigned int u = g[(i + r) * WW + j];
      const float a = (float)(u & 0x1FFu);
      const float bb = (float)(u >> 16);
      mN = fminf(mN, a * a + rr);
      mP = fminf(mP, bb * bb + rr);
    }
  }

  // res = dn*neg - (dp-1)*pos
  const float res = pos ? (1.0f - sqrtf(mP)) : sqrtf(mN);
  float local = tf ? res : 0.0f;

#pragma unroll
  for (int off = 32; off > 0; off >>= 1) local += __shfl_down(local, off);
  __shared__ float red[4];
  const int lane = threadIdx.x & 63, wid = threadIdx.x >> 6;
  if (lane == 0) red[wid] = local;
  __syncthreads();
  if (threadIdx.x == 0)
    wsf[OFF_PART2 + row] = red[0] + red[1] + red[2] + red[3];
}

// ---------------- Stage 3: reduce all partials + finalize scalar ----------------
__global__ __launch_bounds__(256) void stage3_kernel(
    const float* __restrict__ wsf, float* __restrict__ out) {
  const int t = threadIdx.x;
  const float* P = wsf + OFF_P;

  // Global sums over 4096 rows for v=0..3
  float s0 = 0.f, s1 = 0.f, s2 = 0.f, s3 = 0.f;
#pragma unroll
  for (int gi = 0; gi < 16; ++gi) {
    const int idx = t + (gi << 8);
    s0 += P[0 * ROWS + idx];
    s1 += P[1 * ROWS + idx];
    s2 += P[2 * ROWS + idx];
    s3 += P[3 * ROWS + idx];
  }
#pragma unroll
  for (int off = 32; off > 0; off >>= 1) {
    s0 += __shfl_down(s0, off);
    s1 += __shfl_down(s1, off);
    s2 += __shfl_down(s2, off);
    s3 += __shfl_down(s3, off);
  }
  __shared__ float red[4][4];
  const int lane = t & 63, wid = t >> 6;
  if (lane == 0) { red[wid][0] = s0; red[wid][1] = s1; red[wid][2] = s2; red[wid][3] = s3; }

  // Per-sample sums: thread t -> sample b=t>>4, slot m=t&15, each sums 16 rows
  const int b = t >> 4, m = t & 15;
  float pc = 0.f, sb = 0.f;
#pragma unroll
  for (int k = 0; k < 16; ++k) {
    const int idx = (b << 8) + m + (k << 4);
    pc += P[4 * ROWS + idx];
    sb += wsf[OFF_PART2 + idx];
  }
  pc += __shfl_xor(pc, 1); pc += __shfl_xor(pc, 2);
  pc += __shfl_xor(pc, 4); pc += __shfl_xor(pc, 8);
  sb += __shfl_xor(sb, 1); sb += __shfl_xor(sb, 2);
  sb += __shfl_xor(sb, 4); sb += __shfl_xor(sb, 8);
  __shared__ float pcL[16], sbL[16];
  if (m == 0) { pcL[b] = pc; sbL[b] = sb; }
  __syncthreads();

  if (t == 0) {
    const float ceS = red[0][0] + red[1][0] + red[2][0] + red[3][0];
    const float hS  = red[0][1] + red[1][1] + red[2][1] + red[3][1];
    const float htS = red[0][2] + red[1][2] + red[2][2] + red[3][2];
    const float tS  = red[0][3] + red[1][3] + red[2][3] + red[3][3];
    const float ce = ceS * (1.0f / (float)NPIX);
    const float dice_loss = 1.0f - (2.0f * htS + 1.0f) / (hS + tS + 1.0f);
    float lb = 0.0f;
    for (int bb = 0; bb < NB; ++bb)
      lb += (pcL[bb] > 0.0f) ? sbL[bb] * (1.0f / (float)HWSZ) : 0.0f;
    out[0] = ce + dice_loss + lb * lb;
  }
}

extern "C" void kernel_launch(void* const* d_in, const int* in_sizes, int n_in,
                              void* d_out, int out_size, void* d_ws, size_t ws_size,
                              hipStream_t stream) {
  (void)in_sizes; (void)n_in; (void)out_size; (void)ws_size;
  const float* inp = (const float*)d_in[0];
  const int* tgt = (const int*)d_in[1];
  // d_in[2] starget, d_in[3] dice_co, d_in[4] boundary_co: unused by reference
  unsigned int* wsu = (unsigned int*)d_ws;
  float* wsf = (float*)d_ws;
  float* out = (float*)d_out;

  // No atomics anywhere -> no memset needed; all partial slots are fully overwritten.
  stage1_kernel<<<ROWS / 4, 256, 0, stream>>>(inp, tgt, wsu, wsf);
  stage2_kernel<<<ROWS, 256, 0, stream>>>(wsu, wsf);
  stage3_kernel<<<1, 256, 0, stream>>>(wsf, out);
}